// Round 8
// baseline (59.640 us; speedup 1.0000x reference)
//
#include <hip/hip_runtime.h>

#define DYN 16
#define DON 256
#define DIN 256
#define BSN 4096
#define NF 4096   /* DY*DI feature rows */
#define KTOT 512  /* concat K = 2*DI */

typedef unsigned short u16;
typedef __attribute__((ext_vector_type(8))) short bf16x8;
typedef __attribute__((ext_vector_type(4))) float f32x4;
typedef __attribute__((ext_vector_type(4))) unsigned short u16x4;

static __device__ __forceinline__ u16 f2bf(float f) {
  unsigned u = __builtin_bit_cast(unsigned, f);
  u += 0x7fffu + ((u >> 16) & 1u);
  return (u16)(u >> 16);
}
static __device__ __forceinline__ float bf2f(u16 h) {
  unsigned u = ((unsigned)h) << 16;
  return __builtin_bit_cast(float, u);
}

// ---------------------------------------------------------------------------
// Kernel 1: fold rms into weights, concat [Wu | Wl-with-reversed-rms] along K,
// convert to bf16. aprep layout: [4096 rows = d*256+o][512 k], k contiguous.
// ---------------------------------------------------------------------------
__global__ __launch_bounds__(256) void k_prep_w(
    const float* __restrict__ wu, const float* __restrict__ wl,
    const float* __restrict__ rms, u16* __restrict__ aprep) {
  int e = blockIdx.x * 256 + threadIdx.x;   // 262144 threads, 8 elems each
  int row = e >> 6;                         // 0..4095
  int k0 = (e & 63) << 3;                   // 0..504, step 8
  int d = row >> 8;
  const float* src;
  const float* rp;
  if (k0 < 256) {
    src = wu + (size_t)row * 256 + k0;
    rp  = rms + d * 256 + k0;
  } else {
    src = wl + (size_t)row * 256 + (k0 - 256);
    rp  = rms + (DYN - 1 - d) * 256 + (k0 - 256);
  }
  float4 s0 = *reinterpret_cast<const float4*>(src);
  float4 s1 = *reinterpret_cast<const float4*>(src + 4);
  float4 r0 = *reinterpret_cast<const float4*>(rp);
  float4 r1 = *reinterpret_cast<const float4*>(rp + 4);
  bf16x8 o;
  o[0] = (short)f2bf(s0.x * r0.x); o[1] = (short)f2bf(s0.y * r0.y);
  o[2] = (short)f2bf(s0.z * r0.z); o[3] = (short)f2bf(s0.w * r0.w);
  o[4] = (short)f2bf(s1.x * r1.x); o[5] = (short)f2bf(s1.y * r1.y);
  o[6] = (short)f2bf(s1.z * r1.z); o[7] = (short)f2bf(s1.w * r1.w);
  *reinterpret_cast<bf16x8*>(aprep + (size_t)row * KTOT + k0) = o;
}

// ---------------------------------------------------------------------------
// Kernel 2: 128x128 tiled transpose of x with f32->bf16 convert and per-column
// sum(x^2) partials. xbf layout: [BS rows = b][NF cols = f], f contiguous.
// ---------------------------------------------------------------------------
__global__ __launch_bounds__(256) void k_transpose(
    const float* __restrict__ x, u16* __restrict__ xbf,
    float* __restrict__ partial) {
  __shared__ u16 tile[128 * 132];  // [f][b], row stride 132 (264B)
  const int t = threadIdx.x;
  const int bt = blockIdx.x, ft = blockIdx.y;
  const float* xb = x + (size_t)ft * 128 * BSN + bt * 128;
  const int frow = t >> 5, b4 = (t & 31) * 4;
  #pragma unroll
  for (int p = 0; p < 16; ++p) {
    int f = p * 8 + frow;
    float4 v = *reinterpret_cast<const float4*>(xb + (size_t)f * BSN + b4);
    u16x4 h;
    h[0] = f2bf(v.x); h[1] = f2bf(v.y); h[2] = f2bf(v.z); h[3] = f2bf(v.w);
    *reinterpret_cast<u16x4*>(&tile[f * 132 + b4]) = h;
  }
  __syncthreads();
  const int chunk = t & 15;
  const int bg = t >> 4;
  #pragma unroll
  for (int p = 0; p < 8; ++p) {
    int b = bg + p * 16;
    float s = 0.f;
    bf16x8 w;
    #pragma unroll
    for (int jj = 0; jj < 8; ++jj) {
      int j = (jj + chunk) & 7;  // stagger: break same-column bank aliasing
      u16 v = tile[(chunk * 8 + j) * 132 + b];
      float xv = bf2f(v);
      s += xv * xv;
      w[j] = (short)v;
    }
    *reinterpret_cast<bf16x8*>(
        xbf + (size_t)(bt * 128 + b) * NF + ft * 128 + chunk * 8) = w;
    #pragma unroll
    for (int m = 1; m < 16; m <<= 1) s += __shfl_xor(s, m, 64);
    if (chunk == 0) partial[ft * BSN + bt * 128 + b] = s;
  }
}

// ---------------------------------------------------------------------------
// Kernel 3: persistent dual-tile bf16 MFMA GEMM.
// 512 blocks (= exactly 2/CU, ALL resident, single round). Each block owns
// the tile PAIR {(d,mt,nt),(15-d,mt,nt)} which reads IDENTICAL x bytes:
// per kt stage A(x-slice) ONCE + two weight tiles (Bd, B15) -> staging -25%,
// A-frag ds_reads shared, prologue/epilogue once per block.
// Operand swap: A = xbf (M=batch) so the MFMA C-quad = 4 consecutive batches
// -> float4 epilogue stores (4x fewer store instrs).
// XCD map: d = bid&7 -> per-XCD set = xbf f-slice (4MB) + aprep rows (0.5MB)
// fits L2; the mt-pair (2x readers of each x byte) is co-XCD.
// 3-slot LDS ring, steady s_waitcnt vmcnt(6) (6 loads/stage, 2 stages in
// flight; never drains to 0 until tail). fc folded into prologue.
// Involution swizzle chunk ^ ((chunk>>3)&7) (= byte ^ (((byte>>7)&7)<<4)) at
// pre-swizzled global source + ds_read (R2 measured-zero-conflict math).
// Epilogue: relu(fc[batch]*acc + bias[feature]) as float4 stores.
// ---------------------------------------------------------------------------
__global__ __launch_bounds__(256, 2) void k_gemm(
    const u16* __restrict__ aprep, const u16* __restrict__ xbf,
    const float* __restrict__ partial, const float* __restrict__ bias,
    float* __restrict__ out) {
  extern __shared__ char smem[];
  float* fcl = (float*)smem;                 // 128 floats (this block's batches)
  u16* slots = (u16*)(smem + 512);           // 3 slots x (A|Bd|B15) x 4096 u16
  const int bid = blockIdx.x;
  const int d  = bid & 7;                    // 0..7, locks XCD
  const int mt = (bid >> 3) & 1;
  const int bt = bid >> 4;                   // batch tile 0..31
  const int t = threadIdx.x;
  const int wave = t >> 6, lane = t & 63;
  const int lhi = lane >> 4, llo = lane & 15;
  const int wm = wave >> 1, wn = wave & 1;   // 2 batch-halves x 2 feature-halves
  const int bb0 = bt * 128;
  const int fr1 = d * 256 + mt * 128;
  const int fr2 = (15 - d) * 256 + mt * 128;

  f32x4 acc1[4][4] = {}, acc2[4][4] = {};

  auto stage = [&](int slot, int kt) {
    const int fbase = (kt < 8) ? (d * 256 + kt * 32)
                               : ((15 - d) * 256 + (kt - 8) * 32);
    const int k1 = kt * 32;
    const int k2 = (kt ^ 8) * 32;            // tile2's k for the same f-slice
    char* sA  = (char*)(slots + slot * 12288);
    char* sBd = sA + 8192;
    char* sB2 = sA + 16384;
    #pragma unroll
    for (int j = 0; j < 2; ++j) {
      int c = j * 256 + t;              // physical 16B chunk index (0..511)
      int cl = c ^ ((c >> 3) & 7);      // logical chunk (involution)
      int r = cl >> 2, kc = cl & 3;     // logical row / k-octet
      unsigned lbase = (unsigned)((j * 256 + wave * 64) * 16);
      const u16* ga  = xbf   + (size_t)(bb0 + r) * NF   + fbase + kc * 8;
      const u16* gbd = aprep + (size_t)(fr1 + r) * KTOT + k1 + kc * 8;
      const u16* gb2 = aprep + (size_t)(fr2 + r) * KTOT + k2 + kc * 8;
      __builtin_amdgcn_global_load_lds(
          (const __attribute__((address_space(1))) unsigned int*)ga,
          (__attribute__((address_space(3))) unsigned int*)(sA + lbase),
          16, 0, 0);
      __builtin_amdgcn_global_load_lds(
          (const __attribute__((address_space(1))) unsigned int*)gbd,
          (__attribute__((address_space(3))) unsigned int*)(sBd + lbase),
          16, 0, 0);
      __builtin_amdgcn_global_load_lds(
          (const __attribute__((address_space(1))) unsigned int*)gb2,
          (__attribute__((address_space(3))) unsigned int*)(sB2 + lbase),
          16, 0, 0);
    }
  };

  const int kmask = ((llo >> 1) & 7) << 4;   // thread-constant swizzle mask

  // fc fold first (loads retire before staging loads -> no vmcnt interference)
  if (t < 128) {
    float fs = 0.f;
    #pragma unroll
    for (int i = 0; i < 32; ++i) fs += partial[i * BSN + bb0 + t];
    fcl[t] = rsqrtf(fs * (1.0f / 4096.0f) + 1e-6f);
  }
  stage(0, 0);
  stage(1, 1);
  asm volatile("s_waitcnt vmcnt(6)\n\ts_barrier" ::: "memory");

  for (int kt = 0; kt < 16; ++kt) {
    const int slot = kt % 3;
    if (kt < 14) stage((kt + 2) % 3, kt + 2);

    const char* sA  = (const char*)(slots + slot * 12288);
    const char* sBd = sA + 8192;
    const char* sB2 = sA + 16384;
    bf16x8 af[4], b1[4], b2[4];
    #pragma unroll
    for (int m = 0; m < 4; ++m) {
      int rowa = wm * 64 + m * 16 + llo;
      int offa = (rowa * 64 + lhi * 16) ^ kmask;
      af[m] = *reinterpret_cast<const bf16x8*>(sA + offa);
    }
    #pragma unroll
    for (int n = 0; n < 4; ++n) {
      int rowb = wn * 64 + n * 16 + llo;
      int offb = (rowb * 64 + lhi * 16) ^ kmask;
      b1[n] = *reinterpret_cast<const bf16x8*>(sBd + offb);
      b2[n] = *reinterpret_cast<const bf16x8*>(sB2 + offb);
    }
    __builtin_amdgcn_s_setprio(1);
    #pragma unroll
    for (int m = 0; m < 4; ++m)
      #pragma unroll
      for (int n = 0; n < 4; ++n)
        acc1[m][n] = __builtin_amdgcn_mfma_f32_16x16x32_bf16(
            af[m], b1[n], acc1[m][n], 0, 0, 0);
    #pragma unroll
    for (int m = 0; m < 4; ++m)
      #pragma unroll
      for (int n = 0; n < 4; ++n)
        acc2[m][n] = __builtin_amdgcn_mfma_f32_16x16x32_bf16(
            af[m], b2[n], acc2[m][n], 0, 0, 0);
    __builtin_amdgcn_s_setprio(0);

    if (kt < 14) {
      asm volatile("s_waitcnt vmcnt(6)\n\ts_barrier" ::: "memory");
    } else if (kt == 14) {
      asm volatile("s_waitcnt vmcnt(0)\n\ts_barrier" ::: "memory");
    }
  }

  // Epilogue: y[feature][batch] = relu(fc[batch]*acc + bias[feature]);
  // per lane: feature = col, batch quad = row -> contiguous float4 store.
  float4 fcq[4];
  #pragma unroll
  for (int m = 0; m < 4; ++m)
    fcq[m] = *reinterpret_cast<const float4*>(&fcl[wm * 64 + m * 16 + lhi * 4]);
  const int bbase = bb0 + wm * 64 + lhi * 4;
  #pragma unroll
  for (int n = 0; n < 4; ++n) {
    int f1 = fr1 + wn * 64 + n * 16 + llo;
    int f2 = fr2 + wn * 64 + n * 16 + llo;
    float bv1 = bias[f1], bv2 = bias[f2];
    #pragma unroll
    for (int m = 0; m < 4; ++m) {
      float4 v1, v2;
      #pragma unroll
      for (int r = 0; r < 4; ++r) {
        float fcr = (r == 0) ? fcq[m].x : (r == 1) ? fcq[m].y
                    : (r == 2) ? fcq[m].z : fcq[m].w;
        float a1 = acc1[m][n][r] * fcr + bv1;
        float a2 = acc2[m][n][r] * fcr + bv2;
        ((float*)&v1)[r] = fmaxf(a1, 0.f);
        ((float*)&v2)[r] = fmaxf(a2, 0.f);
      }
      *reinterpret_cast<float4*>(out + (size_t)f1 * BSN + bbase + m * 16) = v1;
      *reinterpret_cast<float4*>(out + (size_t)f2 * BSN + bbase + m * 16) = v2;
    }
  }
}

extern "C" void kernel_launch(void* const* d_in, const int* in_sizes, int n_in,
                              void* d_out, int out_size, void* d_ws, size_t ws_size,
                              hipStream_t stream) {
  (void)in_sizes; (void)n_in; (void)out_size; (void)ws_size;
  const float* x    = (const float*)d_in[0];
  const float* rms  = (const float*)d_in[1];
  const float* wu   = (const float*)d_in[2];
  const float* wl   = (const float*)d_in[3];
  const float* bias = (const float*)d_in[4];
  float* out = (float*)d_out;

  char* ws = (char*)d_ws;
  u16* xbf      = (u16*)ws;                      // 32 MiB  (x^T bf16)
  u16* aprep    = (u16*)(ws + 33554432);         // 4 MiB   (folded weights)
  float* partial = (float*)(ws + 37748736);      // 512 KiB (sumsq partials)

  k_prep_w<<<1024, 256, 0, stream>>>(wu, wl, rms, aprep);
  k_transpose<<<dim3(32, 32), 256, 0, stream>>>(x, xbf, partial);
  k_gemm<<<512, 256, 74240, stream>>>(aprep, xbf, partial, bias, out);
}